// Round 1
// baseline (164.182 us; speedup 1.0000x reference)
//
#include <hip/hip_runtime.h>
#include <math.h>

#define F 128
#define HID 32
#define NH 4
#define TILE 64
#define FEA_STRIDE 130  // 128 + 2 pad floats (row stride); conflict-free phase-A reads

__device__ __forceinline__ float silu_f(float x) {
    return x / (1.0f + __expf(-x));
}

// Scatter segment boundaries: starts[b] = first atom index with seg_id >= b.
__global__ void seg_starts_kernel(const int* __restrict__ seg, int* __restrict__ starts,
                                  int N, int B) {
    int i = blockIdx.x * blockDim.x + threadIdx.x;
    if (i >= N) return;
    int id = seg[i];
    if (i == 0) {
        for (int b = 0; b <= id; ++b) starts[b] = 0;
    } else {
        int prev = seg[i - 1];
        for (int b = prev + 1; b <= id; ++b) starts[b] = i;
    }
    if (i == N - 1) {
        for (int b = id + 1; b <= B; ++b) starts[b] = N;
    }
}

// One block per crystal. Flash-style online segment softmax over heads,
// fused with the key-MLP and the weighted feature reduction + output proj.
__global__ __launch_bounds__(256) void attn_readout_kernel(
    const float* __restrict__ atom_fea,
    const int* __restrict__ starts,
    const float* __restrict__ W1, const float* __restrict__ b1,
    const float* __restrict__ W2, const float* __restrict__ b2,
    const float* __restrict__ Wp, const float* __restrict__ bp,
    float* __restrict__ out) {
    __shared__ float sW1[F * HID];              // 16 KB, [k][h]
    __shared__ float sW2[HID * NH];             // 512 B, [h][j]
    __shared__ float sFea[TILE * FEA_STRIDE];   // 33.25 KB
    __shared__ float sU[768];                   // union: {TL[256], TW[256]} | {wacc[512], part[256]}

    const int t = threadIdx.x;
    const int b = blockIdx.x;
    const int start = starts[b];
    const int end = starts[b + 1];

    // Stage W1, W2 into LDS (coalesced float4).
    {
        const float4* src = (const float4*)W1;
        float4* dst = (float4*)sW1;
        #pragma unroll
        for (int q = t; q < (F * HID) / 4; q += 256) dst[q] = src[q];
        if (t < (HID * NH) / 4) ((float4*)sW2)[t] = ((const float4*)W2)[t];
    }

    const int g = t & 3;          // hid group: h in [8g, 8g+8)
    const int g8 = g * 8;
    const int slot = t >> 2;      // atom slot within tile (0..63)
    const int head = t >> 6;      // head owned in softmax/accumulate (wave index)
    const int f0 = (t & 63) * 2;  // feature pair owned in accumulate

    float b1r[8];
    #pragma unroll
    for (int i = 0; i < 8; ++i) b1r[i] = b1[g8 + i];
    const float b2g = b2[g];

    float m_run = -INFINITY;  // per-wave == per-head running max (all lanes replicate)
    float s_run = 0.0f;       // running sum of exp
    float acc0 = 0.0f, acc1 = 0.0f;  // weighted feature accumulators for (head, f0/f0+1)

    float* sTL = sU;        // [64][4] tile logits
    float* sTW = sU + 256;  // [64][4] tile exp-weights

    __syncthreads();  // W1/W2 staged

    for (int a0 = start; a0 < end; a0 += TILE) {
        const int T = min(TILE, end - a0);

        // ---- stage T atom rows (coalesced float2, padded LDS rows) ----
        {
            const float2* src = (const float2*)atom_fea + (size_t)a0 * (F / 2);
            for (int q = t; q < T * (F / 2); q += 256) {
                int r = q >> 6;  // F/2 = 64 float2 per row
                int c = q & 63;
                *(float2*)&sFea[r * FEA_STRIDE + c * 2] = src[(size_t)r * (F / 2) + c];
            }
        }
        __syncthreads();

        // ---- phase A: key-MLP logits for this tile ----
        if (slot < T) {
            float hid[8];
            #pragma unroll
            for (int i = 0; i < 8; ++i) hid[i] = b1r[i];
            const float* arow = &sFea[slot * FEA_STRIDE];
            #pragma unroll 4
            for (int k = 0; k < F; ++k) {
                float av = arow[k];
                float4 wa = *(const float4*)&sW1[k * HID + g8];
                float4 wb = *(const float4*)&sW1[k * HID + g8 + 4];
                hid[0] = fmaf(av, wa.x, hid[0]);
                hid[1] = fmaf(av, wa.y, hid[1]);
                hid[2] = fmaf(av, wa.z, hid[2]);
                hid[3] = fmaf(av, wa.w, hid[3]);
                hid[4] = fmaf(av, wb.x, hid[4]);
                hid[5] = fmaf(av, wb.y, hid[5]);
                hid[6] = fmaf(av, wb.z, hid[6]);
                hid[7] = fmaf(av, wb.w, hid[7]);
            }
            float p[4] = {0.0f, 0.0f, 0.0f, 0.0f};
            #pragma unroll
            for (int i = 0; i < 8; ++i) {
                float sv = silu_f(hid[i]);
                #pragma unroll
                for (int j = 0; j < 4; ++j) p[j] = fmaf(sv, sW2[(g8 + i) * NH + j], p[j]);
            }
            // reduce the 4-lane split of the hid dimension
            #pragma unroll
            for (int j = 0; j < 4; ++j) {
                p[j] += __shfl_xor(p[j], 1);
                p[j] += __shfl_xor(p[j], 2);
            }
            sTL[slot * NH + g] = p[g] + b2g;  // lane g writes logit for head g
        }
        __syncthreads();

        // ---- online softmax update: wave w owns head w ----
        {
            const int lane = t & 63;
            float v = (lane < T) ? sTL[lane * NH + head] : -INFINITY;
            float mt = v;
            #pragma unroll
            for (int m = 1; m < 64; m <<= 1) mt = fmaxf(mt, __shfl_xor(mt, m));
            float m_new = fmaxf(m_run, mt);
            float r = __expf(m_run - m_new);  // first tile: exp(-inf)=0
            float e = (lane < T) ? __expf(v - m_new) : 0.0f;
            sTW[lane * NH + head] = e;  // same wave reads below; no barrier needed
            float se = e;
            #pragma unroll
            for (int m = 1; m < 64; m <<= 1) se += __shfl_xor(se, m);
            s_run = fmaf(s_run, r, se);
            m_run = m_new;
            acc0 *= r;
            acc1 *= r;
        }

        // ---- weighted accumulate: thread owns (head, f0..f0+1) ----
        #pragma unroll 4
        for (int a = 0; a < T; ++a) {
            float w = sTW[a * NH + head];
            float2 v = *(const float2*)&sFea[a * FEA_STRIDE + f0];
            acc0 = fmaf(w, v.x, acc0);
            acc1 = fmaf(w, v.y, acc1);
        }
        __syncthreads();  // protect sFea/sTL/sTW before next tile
    }

    // ---- finalize softmax normalization ----
    float inv = (s_run > 0.0f) ? 1.0f / s_run : 0.0f;
    acc0 *= inv;
    acc1 *= inv;

    // ---- output projection: out[b] = silu(wacc @ Wp + bp) ----
    float* sWacc = sU;        // [512] = (H,F) flattened h*F+f
    float* sPart = sU + 512;  // [256]
    sWacc[head * F + f0] = acc0;
    sWacc[head * F + f0 + 1] = acc1;
    __syncthreads();
    {
        const int f = t & 127;
        const int half = t >> 7;
        float sum = 0.0f;
        const float* wp = Wp + (size_t)(half * 256) * F + f;
        const float* wa = &sWacc[half * 256];
        #pragma unroll 8
        for (int k = 0; k < 256; ++k) sum = fmaf(wa[k], wp[(size_t)k * F], sum);
        sPart[t] = sum;
    }
    __syncthreads();
    if (t < 128) {
        float tot = sPart[t] + sPart[t + 128] + bp[t];
        out[(size_t)b * F + t] = silu_f(tot);
    }
}

extern "C" void kernel_launch(void* const* d_in, const int* in_sizes, int n_in,
                              void* d_out, int out_size, void* d_ws, size_t ws_size,
                              hipStream_t stream) {
    const float* atom_fea = (const float*)d_in[0];
    const int* seg = (const int*)d_in[1];
    const float* W1 = (const float*)d_in[3];
    const float* b1 = (const float*)d_in[4];
    const float* W2 = (const float*)d_in[5];
    const float* b2 = (const float*)d_in[6];
    const float* Wp = (const float*)d_in[7];
    const float* bp = (const float*)d_in[8];
    float* out = (float*)d_out;

    const int N = in_sizes[0] / F;
    const int B = out_size / F;
    int* starts = (int*)d_ws;  // (B+1) ints

    seg_starts_kernel<<<(N + 255) / 256, 256, 0, stream>>>(seg, starts, N, B);
    attn_readout_kernel<<<B, 256, 0, stream>>>(atom_fea, starts, W1, b1, W2, b2, Wp, bp, out);
}

// Round 2
// 119.743 us; speedup vs baseline: 1.3711x; 1.3711x over previous
//
#include <hip/hip_runtime.h>
#include <math.h>

#define F 128
#define HID 32
#define NH 4

__device__ __forceinline__ float silu_f(float x) {
    return x / (1.0f + __expf(-x));
}

// Scatter segment boundaries: starts[b] = first atom index with seg_id >= b.
__global__ void seg_starts_kernel(const int* __restrict__ seg, int* __restrict__ starts,
                                  int N, int B) {
    int i = blockIdx.x * blockDim.x + threadIdx.x;
    if (i >= N) return;
    int id = seg[i];
    if (i == 0) {
        for (int b = 0; b <= id; ++b) starts[b] = 0;
    } else {
        int prev = seg[i - 1];
        for (int b = prev + 1; b <= id; ++b) starts[b] = i;
    }
    if (i == N - 1) {
        for (int b = id + 1; b <= B; ++b) starts[b] = N;
    }
}

// K1: thread-per-atom key MLP. W1/W2/b1/b2 accessed uniformly -> scalar loads,
// atom row streamed 128B-contiguous per lane. logits[N][4].
__global__ __launch_bounds__(256) void logits_kernel(
    const float* __restrict__ atom_fea, const float* __restrict__ W1,
    const float* __restrict__ b1, const float* __restrict__ W2,
    const float* __restrict__ b2, float* __restrict__ logits, int N) {
    int a = blockIdx.x * 256 + threadIdx.x;
    if (a >= N) return;
    float acc[HID];
    #pragma unroll
    for (int h = 0; h < HID; ++h) acc[h] = b1[h];
    const float* row = atom_fea + (size_t)a * F;
    for (int c = 0; c < 4; ++c) {   // not unrolled: keep code size I$-friendly
        float fr[32];
        #pragma unroll
        for (int q = 0; q < 8; ++q)
            *(float4*)&fr[q * 4] = *(const float4*)&row[c * 32 + q * 4];
        #pragma unroll
        for (int k = 0; k < 32; ++k) {
            float fk = fr[k];
            const float* w1r = &W1[(c * 32 + k) * HID];  // uniform -> s_load
            #pragma unroll
            for (int h = 0; h < HID; ++h) acc[h] = fmaf(fk, w1r[h], acc[h]);
        }
    }
    float p[NH] = {b2[0], b2[1], b2[2], b2[3]};
    #pragma unroll
    for (int h = 0; h < HID; ++h) {
        float sv = silu_f(acc[h]);
        #pragma unroll
        for (int j = 0; j < NH; ++j) p[j] = fmaf(sv, W2[h * NH + j], p[j]);
    }
    *(float4*)&logits[(size_t)a * NH] = make_float4(p[0], p[1], p[2], p[3]);
}

// K2: wave-per-crystal segment softmax stats. Writes unnormalized exp weights
// wgt[N][4] and per-(crystal,head) 1/denom.
__global__ __launch_bounds__(256) void segstat_kernel(
    const float* __restrict__ logits, const int* __restrict__ starts,
    float* __restrict__ wgt, float* __restrict__ seginv, int B) {
    int b = blockIdx.x * 4 + (threadIdx.x >> 6);
    if (b >= B) return;
    int lane = threadIdx.x & 63;
    int start = starts[b], end = starts[b + 1];
    int head = lane & 3, ao = lane >> 2;
    float m = -INFINITY;
    for (int a0 = start; a0 < end; a0 += 16) {
        int a = a0 + ao;
        if (a < end) m = fmaxf(m, logits[(size_t)a * NH + head]);
    }
    #pragma unroll
    for (int d = 4; d < 64; d <<= 1) m = fmaxf(m, __shfl_xor(m, d));
    float s = 0.0f;
    for (int a0 = start; a0 < end; a0 += 16) {
        int a = a0 + ao;
        if (a < end) {
            float e = __expf(logits[(size_t)a * NH + head] - m);
            wgt[(size_t)a * NH + head] = e;
            s += e;
        }
    }
    #pragma unroll
    for (int d = 4; d < 64; d <<= 1) s += __shfl_xor(s, d);
    if (lane < 4) seginv[b * NH + lane] = (s > 0.0f) ? 1.0f / s : 0.0f;
}

// K3: block-per-crystal weighted feature sum (coalesced full-row reads,
// uniform s_load weights) + fused output projection.
__global__ __launch_bounds__(256) void readout_kernel(
    const float* __restrict__ atom_fea, const float* __restrict__ wgt,
    const float* __restrict__ seginv, const int* __restrict__ starts,
    const float* __restrict__ Wp, const float* __restrict__ bp,
    float* __restrict__ out) {
    __shared__ float sRed[4][NH][F];  // 8 KB
    __shared__ float sWacc[NH * F];   // 2 KB
    __shared__ float sPart[256];      // 1 KB
    const int t = threadIdx.x, b = blockIdx.x;
    const int start = starts[b], end = starts[b + 1];
    const int wv = t >> 6;            // wave id: atom-interleave group
    const int f0 = (t & 63) * 2;      // feature pair
    float acc[NH][2] = {};
    for (int a = start + wv; a < end; a += 4) {
        float2 v = *(const float2*)&atom_fea[(size_t)a * F + f0];     // 512B/wave
        const float4 w4 = *(const float4*)&wgt[(size_t)a * NH];       // uniform -> s_load
        acc[0][0] = fmaf(w4.x, v.x, acc[0][0]); acc[0][1] = fmaf(w4.x, v.y, acc[0][1]);
        acc[1][0] = fmaf(w4.y, v.x, acc[1][0]); acc[1][1] = fmaf(w4.y, v.y, acc[1][1]);
        acc[2][0] = fmaf(w4.z, v.x, acc[2][0]); acc[2][1] = fmaf(w4.z, v.y, acc[2][1]);
        acc[3][0] = fmaf(w4.w, v.x, acc[3][0]); acc[3][1] = fmaf(w4.w, v.y, acc[3][1]);
    }
    #pragma unroll
    for (int h = 0; h < NH; ++h) {
        sRed[wv][h][f0] = acc[h][0];
        sRed[wv][h][f0 + 1] = acc[h][1];
    }
    __syncthreads();
    {
        const int h = t >> 6;  // 256 threads cover 4 heads x 64 fpairs
        const float inv = seginv[b * NH + h];
        float s0 = sRed[0][h][f0] + sRed[1][h][f0] + sRed[2][h][f0] + sRed[3][h][f0];
        float s1 = sRed[0][h][f0 + 1] + sRed[1][h][f0 + 1] + sRed[2][h][f0 + 1] + sRed[3][h][f0 + 1];
        sWacc[h * F + f0] = s0 * inv;
        sWacc[h * F + f0 + 1] = s1 * inv;
    }
    __syncthreads();
    {
        const int f = t & 127, half = t >> 7;
        float sum = 0.0f;
        const float* wp = Wp + (size_t)(half * 256) * F + f;
        const float* wa = &sWacc[half * 256];
        #pragma unroll 8
        for (int k = 0; k < 256; ++k) sum = fmaf(wa[k], wp[(size_t)k * F], sum);
        sPart[t] = sum;
    }
    __syncthreads();
    if (t < 128) out[(size_t)b * F + t] = silu_f(sPart[t] + sPart[t + 128] + bp[t]);
}

extern "C" void kernel_launch(void* const* d_in, const int* in_sizes, int n_in,
                              void* d_out, int out_size, void* d_ws, size_t ws_size,
                              hipStream_t stream) {
    const float* atom_fea = (const float*)d_in[0];
    const int* seg = (const int*)d_in[1];
    const float* W1 = (const float*)d_in[3];
    const float* b1 = (const float*)d_in[4];
    const float* W2 = (const float*)d_in[5];
    const float* b2 = (const float*)d_in[6];
    const float* Wp = (const float*)d_in[7];
    const float* bp = (const float*)d_in[8];
    float* out = (float*)d_out;

    const int N = in_sizes[0] / F;
    const int B = out_size / F;

    // d_ws layout: starts | logits[N*4] | wgt[N*4] | seginv[B*4]
    char* ws = (char*)d_ws;
    int* starts = (int*)ws;
    size_t off = (((size_t)(B + 1) * sizeof(int)) + 255) & ~(size_t)255;
    float* logits = (float*)(ws + off);
    off += (size_t)N * NH * sizeof(float);
    float* wgt = (float*)(ws + off);
    off += (size_t)N * NH * sizeof(float);
    float* seginv = (float*)(ws + off);

    seg_starts_kernel<<<(N + 255) / 256, 256, 0, stream>>>(seg, starts, N, B);
    logits_kernel<<<(N + 255) / 256, 256, 0, stream>>>(atom_fea, W1, b1, W2, b2, logits, N);
    segstat_kernel<<<(B + 3) / 4, 256, 0, stream>>>(logits, starts, wgt, seginv, B);
    readout_kernel<<<B, 256, 0, stream>>>(atom_fea, wgt, seginv, starts, Wp, bp, out);
}